// Round 3
// baseline (763.365 us; speedup 1.0000x reference)
//
#include <hip/hip_runtime.h>
#include <math.h>

typedef _Float16 Hh;
typedef __attribute__((ext_vector_type(8))) _Float16 half8;
typedef __attribute__((ext_vector_type(4))) _Float16 half4;
typedef __attribute__((ext_vector_type(4))) float float4v;

#define B_ 2
#define H_ 16
#define N_ 2048
#define D_ 64
#define ND_ (N_*D_)
#define C1 0.04508422f   // (1/32)*log2(e); softmax in base-2 consistently

// ---------------------------------------------------------------------------
// K1: prep. blocks 0..2047: premix q,k with W_pre -> f16 [b][e][n][d].
//     blocks 2048..3071: transpose v -> f16 vt[b][e][d][j].
// ---------------------------------------------------------------------------
__global__ __launch_bounds__(256) void prep_kernel(const float* __restrict__ q,
    const float* __restrict__ k, const float* __restrict__ v,
    const float* __restrict__ Wpre,
    Hh* __restrict__ qb, Hh* __restrict__ kb, Hh* __restrict__ vt)
{
    int tid = threadIdx.x;
    int bid = blockIdx.x;
    if (bid < 2048) {
        __shared__ float wsh[256];
        wsh[tid] = Wpre[tid];
        __syncthreads();
        int tensor = bid >> 10;
        int gid = ((bid & 1023) << 8) | tid;
        int b = gid >> 17;
        int nd = gid & (ND_-1);
        const float* src = tensor ? k : q;
        Hh* dst = tensor ? kb : qb;
        const float* base = src + (size_t)b*H_*ND_ + nd;
        float x[16];
        #pragma unroll
        for (int f=0; f<16; f++) x[f] = base[(size_t)f*ND_];
        Hh* ob = dst + (size_t)b*H_*ND_ + nd;
        #pragma unroll
        for (int e=0; e<16; e++) {
            float acc = 0.f;
            #pragma unroll
            for (int f=0; f<16; f++) acc += wsh[e*16+f]*x[f];
            ob[(size_t)e*ND_] = (Hh)acc;
        }
    } else {
        __shared__ Hh tile[64][66];
        int tb = bid - 2048;
        int be = tb >> 5;             // b*16+e
        int j0 = (tb & 31) << 6;
        const float* vb = v + (size_t)be*ND_;
        #pragma unroll
        for (int u=0; u<16; u++) {
            int idx = (u<<8) | tid;
            int jp = idx >> 6, d = idx & 63;
            tile[jp][d] = (Hh)vb[(size_t)(j0+jp)*64 + d];
        }
        __syncthreads();
        Hh* vo = vt + (size_t)be*ND_;
        #pragma unroll
        for (int u=0; u<16; u++) {
            int idx = (u<<8) | tid;
            int d = idx >> 6, jp = idx & 63;
            vo[(size_t)d*N_ + j0 + jp] = tile[jp][d];
        }
    }
}

// ---------------------------------------------------------------------------
// K2: denominator partials, split-j. Grid 2048: bid -> (slab s, b, i-tile).
// Block covers j in [256s, 256s+255] (clipped causally); atomicAdds partial
// row-sums of exp2(C1*s) into lacc_g[b,f,i].
// ---------------------------------------------------------------------------
__global__ __launch_bounds__(256) void denom_partial(const Hh* __restrict__ qb,
    const Hh* __restrict__ kb, float* __restrict__ lacc_g)
{
    int bid = blockIdx.x;
    int s = bid & 7;
    int idx = 255 - (bid >> 3);        // big i-tiles first
    int b = idx & 1, it = idx >> 1;
    int i0 = it << 4, imax = i0 + 15;
    int js = s << 8;
    if (js > imax) return;             // inactive slab

    int tid = threadIdx.x;
    int lane = tid & 63, w = tid >> 6;
    int quad = lane >> 4, col = lane & 15;

    if (js + 16*w > imax) return;      // this wave has no causal work at all

    float lacc[64];
    #pragma unroll
    for (int i=0;i<64;i++) lacc[i]=0.f;

    for (int t=0;t<4;t++) {
        int jc = js + t*64 + 16*w;
        if (jc <= imax) {              // wave-uniform
            #pragma unroll
            for (int f=0; f<16; f++) {
                const Hh* qr = qb + ((size_t)(b*16+f)*N_ + i0+col)*64 + quad*8;
                const Hh* kr = kb + ((size_t)(b*16+f)*N_ + jc+col)*64 + quad*8;
                half8 a0 = *(const half8*)qr;
                half8 a1 = *(const half8*)(qr+32);
                half8 b0 = *(const half8*)kr;
                half8 b1 = *(const half8*)(kr+32);
                float4v sv = {0.f,0.f,0.f,0.f};
                sv = __builtin_amdgcn_mfma_f32_16x16x32_f16(a0,b0,sv,0,0,0);
                sv = __builtin_amdgcn_mfma_f32_16x16x32_f16(a1,b1,sv,0,0,0);
                #pragma unroll
                for (int r=0;r<4;r++) {
                    int ir = i0 + quad*4 + r;
                    int jl = jc + col;
                    float ev = (jl <= ir) ? __builtin_amdgcn_exp2f(sv[r]*C1) : 0.f;
                    lacc[f*4+r] += ev;
                }
            }
        }
    }
    #pragma unroll
    for (int f=0; f<16; f++) {
      #pragma unroll
      for (int r=0;r<4;r++) {
        float vs = lacc[f*4+r];
        vs += __shfl_xor(vs, 1);
        vs += __shfl_xor(vs, 2);
        vs += __shfl_xor(vs, 4);
        vs += __shfl_xor(vs, 8);
        if (col == 0)
            unsafeAtomicAdd(&lacc_g[(size_t)(b*16+f)*N_ + i0 + quad*4 + r], vs);
      }
    }
}

// ---------------------------------------------------------------------------
// K3: main fused pass, split-j. Grid 2048: bid -> (slab, b, i-tile); each
// active block handles <=4 j-tiles of 64, atomicAdds fp32 partial O into out.
// Per tile: scores (MFMA f16) -> p=exp2(s*C1-log2 l) -> Pbuf(LDS) ->
// head-mix via mfma_16x16x16f16 -> pm (LDS, XOR-swizzled) -> PV MFMA (vt).
// ---------------------------------------------------------------------------
__global__ __launch_bounds__(256,2) void attend_partial(const Hh* __restrict__ qb,
    const Hh* __restrict__ kb, const Hh* __restrict__ vt,
    const float* __restrict__ lacc_g, const float* __restrict__ Wpost,
    float* __restrict__ out)
{
    __shared__ Hh Pbuf[4][256][20];   // [wave][point=i'*16+j'][f]  40960 B
    __shared__ Hh pm[16][16][68];     // [i'][e][8x8 chunks, chunk ^ (i'&7)] 34816 B
    __shared__ float lgl[16][16];

    int bid = blockIdx.x;
    int sl = bid & 7;
    int idx = 255 - (bid >> 3);
    int b = idx & 1, it = idx >> 1;
    int i0 = it << 4, imax = i0 + 15;
    int js = sl << 8;
    if (js > imax) return;             // inactive slab (uniform, before any barrier)

    int tid = threadIdx.x;
    int lane = tid & 63, w = tid >> 6;
    int quad = lane >> 4, col = lane & 15;

    // log2 of denominators for this i-tile
    lgl[tid>>4][tid&15] =
        __builtin_amdgcn_logf(lacc_g[(size_t)(b*16+(tid>>4))*N_ + i0 + (tid&15)]);

    half4 wf;   // A-frag of W_post for 16x16x16f16: A[m=e=col][k=f=quad*4+j]
    #pragma unroll
    for (int j=0;j<4;j++) wf[j] = (Hh)Wpost[col*16 + quad*4 + j];

    float4v acc[4][4];
    #pragma unroll
    for (int x=0;x<4;x++)
      #pragma unroll
      for (int y=0;y<4;y++) acc[x][y] = (float4v){0.f,0.f,0.f,0.f};

    __syncthreads();

    for (int t=0;t<4;t++) {
        int j0 = js + t*64;
        if (j0 > imax) break;          // block-uniform causal cut
        int jc = j0 + 16*w;
        if (jc <= imax) {
            // ---- scores + exp for all 16 f at this wave's 16-j chunk ----
            #pragma unroll
            for (int f=0; f<16; f++) {
                const Hh* qr = qb + ((size_t)(b*16+f)*N_ + i0+col)*64 + quad*8;
                const Hh* kr = kb + ((size_t)(b*16+f)*N_ + jc+col)*64 + quad*8;
                half8 a0 = *(const half8*)qr;
                half8 a1 = *(const half8*)(qr+32);
                half8 b0 = *(const half8*)kr;
                half8 b1 = *(const half8*)(kr+32);
                float4v sv = {0.f,0.f,0.f,0.f};
                sv = __builtin_amdgcn_mfma_f32_16x16x32_f16(a0,b0,sv,0,0,0);
                sv = __builtin_amdgcn_mfma_f32_16x16x32_f16(a1,b1,sv,0,0,0);
                float4v lg = *(const float4v*)&lgl[f][quad*4];
                #pragma unroll
                for (int r=0;r<4;r++) {
                    int ir = i0 + quad*4 + r;
                    int jl = jc + col;
                    float p = (jl <= ir) ? __builtin_amdgcn_exp2f(sv[r]*C1 - lg[r]) : 0.f;
                    Pbuf[w][(quad*4+r)*16 + col][f] = (Hh)p;
                }
            }
            // ---- head mix: Pm[e][point] = W_post . P  (own-wave LDS only) ----
            #pragma unroll
            for (int g=0; g<16; g++) {
                half4 bf = *(const half4*)&Pbuf[w][g*16 + col][quad*4];
                float4v c = {0.f,0.f,0.f,0.f};
                c = __builtin_amdgcn_mfma_f32_16x16x16f16(wf, bf, c, 0,0,0);
                int jj = 16*w + col;
                int chunk = (jj>>3) ^ (g&7);
                int off = chunk*8 + (jj&7);
                #pragma unroll
                for (int r=0;r<4;r++) pm[g][quad*4+r][off] = (Hh)c[r];
            }
        } else {
            int jj = 16*w + col;
            #pragma unroll
            for (int g=0; g<16; g++) {
                int chunk = (jj>>3) ^ (g&7);
                int off = chunk*8 + (jj&7);
                #pragma unroll
                for (int r=0;r<4;r++) pm[g][quad*4+r][off] = (Hh)0.f;
            }
        }
        __syncthreads();
        // ---- PV: wave w owns e in [4w, 4w+4), full d=64 ----
        #pragma unroll
        for (int el=0; el<4; el++) {
            int e = w*4 + el;
            #pragma unroll
            for (int kc=0; kc<2; kc++) {
                if (j0 + kc*32 <= imax) {       // wave-uniform skip
                    int chunk = (kc*4 + quad) ^ (col & 7);
                    const Hh* pp = &pm[col][e][chunk*8];
                    half4 p0 = *(const half4*)pp;
                    half4 p1 = *(const half4*)(pp+4);
                    half8 af;
                    #pragma unroll
                    for (int z=0;z<4;z++){ af[z]=p0[z]; af[4+z]=p1[z]; }
                    #pragma unroll
                    for (int nc=0; nc<4; nc++) {
                        const Hh* vr = vt + ((size_t)(b*16+e)*64 + nc*16 + col)*N_
                                          + j0 + kc*32 + quad*8;
                        half8 vfr = *(const half8*)vr;
                        acc[el][nc] = __builtin_amdgcn_mfma_f32_16x16x32_f16(af, vfr, acc[el][nc], 0,0,0);
                    }
                }
            }
        }
        __syncthreads();
    }
    // atomic accumulate partial O
    #pragma unroll
    for (int el=0; el<4; el++) {
        int e = w*4 + el;
        #pragma unroll
        for (int nc=0; nc<4; nc++) {
          #pragma unroll
          for (int r=0;r<4;r++)
            unsafeAtomicAdd(&out[((size_t)(b*16+e)*N_ + i0 + quad*4 + r)*64 + nc*16 + col],
                            acc[el][nc][r]);
        }
    }
}

extern "C" void kernel_launch(void* const* d_in, const int* in_sizes, int n_in,
                              void* d_out, int out_size, void* d_ws, size_t ws_size,
                              hipStream_t stream) {
    const float* q     = (const float*)d_in[0];
    const float* k     = (const float*)d_in[1];
    const float* v     = (const float*)d_in[2];
    const float* Wpre  = (const float*)d_in[3];
    const float* Wpost = (const float*)d_in[4];
    float* out = (float*)d_out;

    size_t tsz = (size_t)B_*H_*N_*D_;       // 4 Mi halves = 8 MB each
    Hh* qb = (Hh*)d_ws;
    Hh* kb = qb + tsz;
    Hh* vt = kb + tsz;
    float* lacc = (float*)(vt + tsz);       // 24 MB offset, 256 KB

    hipMemsetAsync(lacc, 0, (size_t)B_*H_*N_*sizeof(float), stream);
    hipMemsetAsync(out, 0, (size_t)out_size*sizeof(float), stream);
    prep_kernel<<<3072, 256, 0, stream>>>(q, k, v, Wpre, qb, kb, vt);
    denom_partial<<<2048, 256, 0, stream>>>(qb, kb, lacc);
    attend_partial<<<2048, 256, 0, stream>>>(qb, kb, vt, lacc, Wpost, out);
}

// Round 4
// 330.576 us; speedup vs baseline: 2.3092x; 2.3092x over previous
//
#include <hip/hip_runtime.h>
#include <math.h>

typedef _Float16 Hh;
typedef __attribute__((ext_vector_type(8))) _Float16 half8;
typedef __attribute__((ext_vector_type(4))) _Float16 half4;
typedef __attribute__((ext_vector_type(4))) float float4v;

#define B_ 2
#define H_ 16
#define N_ 2048
#define D_ 64
#define ND_ (N_*D_)
#define C1 0.04508422f   // (1/32)*log2(e); softmax in base-2 throughout

// ---------------------------------------------------------------------------
// K1: prep.
//  blocks [0,512):  premix q,k with W_pre -> f16 qb/kb [b][e][n][d], float4-wide
//  blocks [512,768): transpose v -> f16 vt2, tile-blocked [be][jt][d][j&31]
// ---------------------------------------------------------------------------
__global__ __launch_bounds__(256) void prep_kernel(const float* __restrict__ q,
    const float* __restrict__ k, const float* __restrict__ v,
    const float* __restrict__ Wpre,
    Hh* __restrict__ qb, Hh* __restrict__ kb, Hh* __restrict__ vt2)
{
    int tid = threadIdx.x;
    int bid = blockIdx.x;
    if (bid < 512) {
        __shared__ float wsh[256];
        wsh[tid] = Wpre[tid];
        __syncthreads();
        int tensor = bid >> 8;
        int g = ((bid & 255) << 8) | tid;     // 0 .. 65535
        int b = g >> 15;
        int r = g & 32767;                    // (n,d4): n*16 + d4
        const float4* src = (const float4*)(tensor ? k : q);
        Hh* dst = tensor ? kb : qb;
        float4 x[16];
        #pragma unroll
        for (int f=0; f<16; f++) x[f] = src[(size_t)(b*16+f)*32768 + r];
        #pragma unroll
        for (int e=0; e<16; e++) {
            float4 a = make_float4(0.f,0.f,0.f,0.f);
            #pragma unroll
            for (int f=0; f<16; f++) {
                float wv = wsh[e*16+f];
                a.x += wv*x[f].x; a.y += wv*x[f].y; a.z += wv*x[f].z; a.w += wv*x[f].w;
            }
            half4 hv; hv[0]=(Hh)a.x; hv[1]=(Hh)a.y; hv[2]=(Hh)a.z; hv[3]=(Hh)a.w;
            *(half4*)(dst + (size_t)(b*16+e)*ND_ + (size_t)r*4) = hv;
        }
    } else {
        __shared__ Hh tile[64*48];            // [d][j], stride 48 halves
        int tb = bid - 512;                   // 0..255
        int be = tb >> 3;                     // 0..31
        int jtg = tb & 7;
        const float4* v4 = (const float4*)v;
        for (int u=0; u<8; u++) {
            int jt = jtg*8 + u;               // 0..63
            #pragma unroll
            for (int p=0; p<2; p++) {
                int j = p*16 + (tid>>4);
                int d4 = tid & 15;
                float4 val = v4[(size_t)be*32768 + (size_t)(jt*32+j)*16 + d4];
                tile[(d4*4+0)*48 + j] = (Hh)val.x;
                tile[(d4*4+1)*48 + j] = (Hh)val.y;
                tile[(d4*4+2)*48 + j] = (Hh)val.z;
                tile[(d4*4+3)*48 + j] = (Hh)val.w;
            }
            __syncthreads();
            {
                int d = tid >> 2;
                int jc = (tid & 3) * 8;
                half8 o;
                #pragma unroll
                for (int z=0; z<8; z++) o[z] = tile[d*48 + jc + z];
                *(half8*)(vt2 + ((size_t)(be*64) + jt)*2048 + (size_t)tid*8) = o;
            }
            __syncthreads();
        }
    }
}

// ---------------------------------------------------------------------------
// K2: denominators, split-j, cooperative K staging.
// Grid 1024: s = bid&7 (slab of 8 j-tiles), (b,it) from descending idx.
// 512 threads / 8 waves; wave w owns f = {2w, 2w+1}. Q frags in registers.
// lacc_g[b,f,i] += sum_j exp2(C1*s) via unsafeAtomicAdd.
// ---------------------------------------------------------------------------
__global__ __launch_bounds__(512,2) void denom_kernel(const Hh* __restrict__ qb,
    const Hh* __restrict__ kb, float* __restrict__ lacc_g)
{
    __shared__ Hh Ksh[16*32*64];   // [f][j][d-chunks XOR (j&7)]  64 KB

    int bid = blockIdx.x;
    int s = bid & 7;
    int rem = bid >> 3;
    int idx = 127 - rem;
    int b = idx & 1, it = idx >> 1;
    if (8*s > it) return;
    int i0 = it * 32;
    int jt_end = (8*s + 7 < it) ? (8*s + 7) : it;

    int tid = threadIdx.x;
    int lane = tid & 63, w = tid >> 6;
    int qd = lane >> 4, c = lane & 15;

    // Q A-frags in regs: a[fi][ig][kd]
    half8 af[2][2][2];
    #pragma unroll
    for (int fi=0; fi<2; fi++) {
        int f = 2*w + fi;
        #pragma unroll
        for (int ig=0; ig<2; ig++) {
            const Hh* qr = qb + (size_t)((b*16+f)*N_ + i0 + ig*16 + c)*64 + qd*8;
            af[fi][ig][0] = *(const half8*)qr;
            af[fi][ig][1] = *(const half8*)(qr + 32);
        }
    }

    float lacc[2][2][4];
    #pragma unroll
    for (int fi=0;fi<2;fi++) for (int ig=0;ig<2;ig++) for (int r=0;r<4;r++) lacc[fi][ig][r]=0.f;

    for (int jt = 8*s; jt <= jt_end; jt++) {
        int j0 = jt * 32;
        // stage full K tile: 4096 16B-chunks over 512 threads
        #pragma unroll
        for (int u=0; u<8; u++) {
            int ch = u*512 + tid;
            int f = ch >> 8, r = ch & 255;
            int j = r >> 3, dc = r & 7;
            half8 val = *(const half8*)(kb + (size_t)((b*16+f)*N_ + j0 + j)*64 + dc*8);
            *(half8*)&Ksh[(f*32 + j)*64 + ((dc ^ (j&7))*8)] = val;
        }
        __syncthreads();
        #pragma unroll
        for (int fi=0; fi<2; fi++) {
            int f = 2*w + fi;
            #pragma unroll
            for (int ig=0; ig<2; ig++) {
                #pragma unroll
                for (int jh=0; jh<2; jh++) {
                    half8 b0 = *(const half8*)&Ksh[(f*32 + jh*16 + c)*64 + ((qd ^ (c&7))*8)];
                    half8 b1 = *(const half8*)&Ksh[(f*32 + jh*16 + c)*64 + (((4+qd) ^ (c&7))*8)];
                    float4v sv = {0.f,0.f,0.f,0.f};
                    sv = __builtin_amdgcn_mfma_f32_16x16x32_f16(af[fi][ig][0], b0, sv, 0,0,0);
                    sv = __builtin_amdgcn_mfma_f32_16x16x32_f16(af[fi][ig][1], b1, sv, 0,0,0);
                    #pragma unroll
                    for (int r=0; r<4; r++) {
                        int i = i0 + ig*16 + qd*4 + r;
                        int j = j0 + jh*16 + c;
                        float ev = (j <= i) ? __builtin_amdgcn_exp2f(sv[r]*C1) : 0.f;
                        lacc[fi][ig][r] += ev;
                    }
                }
            }
        }
        __syncthreads();
    }
    // reduce over the 16 column-lanes, atomically accumulate
    #pragma unroll
    for (int fi=0; fi<2; fi++) {
        int f = 2*w + fi;
        #pragma unroll
        for (int ig=0; ig<2; ig++) {
            #pragma unroll
            for (int r=0; r<4; r++) {
                float vs = lacc[fi][ig][r];
                vs += __shfl_xor(vs, 1);
                vs += __shfl_xor(vs, 2);
                vs += __shfl_xor(vs, 4);
                vs += __shfl_xor(vs, 8);
                if (c == 0)
                    unsafeAtomicAdd(&lacc_g[(size_t)(b*16+f)*N_ + i0 + ig*16 + qd*4 + r], vs);
            }
        }
    }
}

// ---------------------------------------------------------------------------
// K3: main fused pass. 512 threads / 8 waves, 32i x 32j tiles, split-j slabs.
// Wave w: scores for f=w (K-half0) and f=w+8 (K-half1); mix groups i=4w..4w+3
// (in-place in Ebuf); PV for e={2w,2w+1}. K 32KB + V 64KB + E 32KB = 128 KB.
// Partial O accumulated into out via unsafeAtomicAdd.
// ---------------------------------------------------------------------------
__global__ __launch_bounds__(512,2) void attend_kernel(const Hh* __restrict__ qb,
    const Hh* __restrict__ kb, const Hh* __restrict__ vt2,
    const float* __restrict__ lacc_g, const float* __restrict__ Wpost,
    float* __restrict__ out)
{
    __shared__ Hh Ksh[8*32*64];    // [fl][j][d-chunks XOR (j&7)]   32 KB
    __shared__ Hh Vsh[16*64*32];   // [e][d][j-chunks XOR (d&3)]    64 KB
    __shared__ Hh Ebuf[16*32*32];  // [slot][i][j-chunks XOR (i&3)] 32 KB

    int bid = blockIdx.x;
    int s = bid & 7;
    int rem = bid >> 3;
    int idx = 127 - rem;
    int b = idx & 1, it = idx >> 1;
    if (8*s > it) return;
    int i0 = it * 32;
    int jt_end = (8*s + 7 < it) ? (8*s + 7) : it;

    int tid = threadIdx.x;
    int lane = tid & 63, w = tid >> 6;
    int qd = lane >> 4, c = lane & 15;

    // Q A-frags: fi=0 -> f=w, fi=1 -> f=w+8
    half8 af[2][2][2];
    float lgr[2][2][4];
    #pragma unroll
    for (int fi=0; fi<2; fi++) {
        int f = w + 8*fi;
        #pragma unroll
        for (int ig=0; ig<2; ig++) {
            const Hh* qr = qb + (size_t)((b*16+f)*N_ + i0 + ig*16 + c)*64 + qd*8;
            af[fi][ig][0] = *(const half8*)qr;
            af[fi][ig][1] = *(const half8*)(qr + 32);
            #pragma unroll
            for (int r=0; r<4; r++)
                lgr[fi][ig][r] = __builtin_amdgcn_logf(
                    lacc_g[(size_t)(b*16+f)*N_ + i0 + ig*16 + qd*4 + r]);
        }
    }
    // W_post A-frag for mix (16x16x16): A[m=e=c][k=f=qd*4+z]
    half4 wf;
    #pragma unroll
    for (int z=0; z<4; z++) wf[z] = (Hh)Wpost[c*16 + qd*4 + z];

    float4v acc[2][2][4];
    #pragma unroll
    for (int el=0; el<2; el++) for (int ig=0; ig<2; ig++) for (int nc=0; nc<4; nc++)
        acc[el][ig][nc] = (float4v){0.f,0.f,0.f,0.f};

    for (int jt = 8*s; jt <= jt_end; jt++) {
        int j0 = jt * 32;
        // ---- stage K-half0 (f 0..7) + V ----
        #pragma unroll
        for (int u=0; u<4; u++) {
            int ch = u*512 + tid;
            int fl = ch >> 8, r = ch & 255;
            int j = r >> 3, dc = r & 7;
            half8 val = *(const half8*)(kb + (size_t)((b*16+fl)*N_ + j0 + j)*64 + dc*8);
            *(half8*)&Ksh[(fl*32 + j)*64 + ((dc ^ (j&7))*8)] = val;
        }
        #pragma unroll
        for (int u=0; u<8; u++) {
            int ch = u*512 + tid;
            int e = ch >> 8, r = ch & 255;
            int d = r >> 2, jc = r & 3;
            half8 val = *(const half8*)(vt2 + (size_t)((b*16+e)*64 + jt)*2048 + d*32 + jc*8);
            *(half8*)&Vsh[(e*64 + d)*32 + ((jc ^ (d&3))*8)] = val;
        }
        __syncthreads();
        // ---- scores half0: f = w ----
        #pragma unroll
        for (int ig=0; ig<2; ig++) {
            #pragma unroll
            for (int jh=0; jh<2; jh++) {
                half8 b0 = *(const half8*)&Ksh[(w*32 + jh*16 + c)*64 + ((qd ^ (c&7))*8)];
                half8 b1 = *(const half8*)&Ksh[(w*32 + jh*16 + c)*64 + (((4+qd) ^ (c&7))*8)];
                float4v sv = {0.f,0.f,0.f,0.f};
                sv = __builtin_amdgcn_mfma_f32_16x16x32_f16(af[0][ig][0], b0, sv, 0,0,0);
                sv = __builtin_amdgcn_mfma_f32_16x16x32_f16(af[0][ig][1], b1, sv, 0,0,0);
                #pragma unroll
                for (int r=0; r<4; r++) {
                    int i = i0 + ig*16 + qd*4 + r;
                    int j = j0 + jh*16 + c;
                    float p = (j <= i) ? __builtin_amdgcn_exp2f(sv[r]*C1 - lgr[0][ig][r]) : 0.f;
                    int il = ig*16 + qd*4 + r;
                    int chunk = (jh*2 + (c>>3)) ^ (il & 3);
                    Ebuf[(w*32 + il)*32 + chunk*8 + (c&7)] = (Hh)p;
                }
            }
        }
        __syncthreads();
        // ---- stage K-half1 (f 8..15) ----
        #pragma unroll
        for (int u=0; u<4; u++) {
            int ch = u*512 + tid;
            int fl = ch >> 8, r = ch & 255;
            int j = r >> 3, dc = r & 7;
            half8 val = *(const half8*)(kb + (size_t)((b*16+8+fl)*N_ + j0 + j)*64 + dc*8);
            *(half8*)&Ksh[(fl*32 + j)*64 + ((dc ^ (j&7))*8)] = val;
        }
        __syncthreads();
        // ---- scores half1: f = w+8 ----
        #pragma unroll
        for (int ig=0; ig<2; ig++) {
            #pragma unroll
            for (int jh=0; jh<2; jh++) {
                half8 b0 = *(const half8*)&Ksh[(w*32 + jh*16 + c)*64 + ((qd ^ (c&7))*8)];
                half8 b1 = *(const half8*)&Ksh[(w*32 + jh*16 + c)*64 + (((4+qd) ^ (c&7))*8)];
                float4v sv = {0.f,0.f,0.f,0.f};
                sv = __builtin_amdgcn_mfma_f32_16x16x32_f16(af[1][ig][0], b0, sv, 0,0,0);
                sv = __builtin_amdgcn_mfma_f32_16x16x32_f16(af[1][ig][1], b1, sv, 0,0,0);
                #pragma unroll
                for (int r=0; r<4; r++) {
                    int i = i0 + ig*16 + qd*4 + r;
                    int j = j0 + jh*16 + c;
                    float p = (j <= i) ? __builtin_amdgcn_exp2f(sv[r]*C1 - lgr[1][ig][r]) : 0.f;
                    int il = ig*16 + qd*4 + r;
                    int chunk = (jh*2 + (c>>3)) ^ (il & 3);
                    Ebuf[((w+8)*32 + il)*32 + chunk*8 + (c&7)] = (Hh)p;
                }
            }
        }
        __syncthreads();
        // ---- head-mix, in place. wave w owns i-rows 4w..4w+3 (groups 8w..8w+7)
        #pragma unroll
        for (int gl=0; gl<8; gl++) {
            int g = 8*w + gl;
            int il = g >> 1;
            int jh = g & 1;
            int chunk = (jh*2 + (c>>3)) ^ (il & 3);
            int joff = chunk*8 + (c&7);
            half4 bf;
            #pragma unroll
            for (int z=0; z<4; z++)
                bf[z] = Ebuf[((qd*4+z)*32 + il)*32 + joff];
            float4v cc = {0.f,0.f,0.f,0.f};
            cc = __builtin_amdgcn_mfma_f32_16x16x16f16(wf, bf, cc, 0,0,0);
            #pragma unroll
            for (int r=0; r<4; r++)
                Ebuf[((qd*4+r)*32 + il)*32 + joff] = (Hh)cc[r];
        }
        __syncthreads();
        // ---- PV: wave w owns e = {2w, 2w+1} ----
        #pragma unroll
        for (int el=0; el<2; el++) {
            int e = 2*w + el;
            #pragma unroll
            for (int ig=0; ig<2; ig++) {
                half8 pa = *(const half8*)&Ebuf[(e*32 + ig*16 + c)*32 + ((qd ^ (c&3))*8)];
                #pragma unroll
                for (int nc=0; nc<4; nc++) {
                    half8 vb = *(const half8*)&Vsh[(e*64 + nc*16 + c)*32 + ((qd ^ (c&3))*8)];
                    acc[el][ig][nc] = __builtin_amdgcn_mfma_f32_16x16x32_f16(pa, vb, acc[el][ig][nc], 0,0,0);
                }
            }
        }
        __syncthreads();
    }
    // ---- accumulate partial O ----
    #pragma unroll
    for (int el=0; el<2; el++) {
        int e = 2*w + el;
        #pragma unroll
        for (int ig=0; ig<2; ig++) {
            #pragma unroll
            for (int nc=0; nc<4; nc++) {
                #pragma unroll
                for (int r=0; r<4; r++)
                    unsafeAtomicAdd(&out[(size_t)((b*16+e)*N_ + i0 + ig*16 + qd*4 + r)*64 + nc*16 + c],
                                    acc[el][ig][nc][r]);
            }
        }
    }
}

extern "C" void kernel_launch(void* const* d_in, const int* in_sizes, int n_in,
                              void* d_out, int out_size, void* d_ws, size_t ws_size,
                              hipStream_t stream) {
    const float* q     = (const float*)d_in[0];
    const float* k     = (const float*)d_in[1];
    const float* v     = (const float*)d_in[2];
    const float* Wpre  = (const float*)d_in[3];
    const float* Wpost = (const float*)d_in[4];
    float* out = (float*)d_out;

    size_t tsz = (size_t)B_*H_*N_*D_;       // 4 Mi halves = 8 MB each
    Hh* qb = (Hh*)d_ws;
    Hh* kb = qb + tsz;
    Hh* vt2 = kb + tsz;
    float* lacc = (float*)(vt2 + tsz);      // 24 MB offset, 256 KB

    hipMemsetAsync(lacc, 0, (size_t)B_*H_*N_*sizeof(float), stream);
    hipMemsetAsync(out, 0, (size_t)out_size*sizeof(float), stream);
    prep_kernel<<<768, 256, 0, stream>>>(q, k, v, Wpre, qb, kb, vt2);
    denom_kernel<<<1024, 512, 0, stream>>>(qb, kb, lacc);
    attend_kernel<<<1024, 512, 0, stream>>>(qb, kb, vt2, lacc, Wpost, out);
}